// Round 5
// baseline (225.273 us; speedup 1.0000x reference)
//
#include <hip/hip_runtime.h>
#include <hip/hip_fp16.h>
#include <math.h>

typedef unsigned int u32;
typedef unsigned short u16;

#define T_ 16
#define B_ 32
#define S_ 256
#define H_ 256
#define E_ 300
#define V_ 1000

typedef _Float16 h2_t __attribute__((ext_vector_type(2)));
typedef __fp16  fp16v2 __attribute__((ext_vector_type(2)));

__device__ __forceinline__ float fast_tanh(float x) {
    return 1.0f - 2.0f / (__expf(2.0f * x) + 1.0f);
}
__device__ __forceinline__ float fast_sigm(float x) {
    return 1.0f / (1.0f + __expf(-x));
}
__device__ __forceinline__ float bf2f(u16 x) { return __uint_as_float(((u32)x) << 16); }
__device__ __forceinline__ float blo(u32 u) { return __uint_as_float(u << 16); }
__device__ __forceinline__ float bhi(u32 u) { return __uint_as_float(u & 0xffff0000u); }
__device__ __forceinline__ u16 f2bf(float f) {
    u32 u = __float_as_uint(f);
    u32 r = (u + 0x7fffu + ((u >> 16) & 1u)) >> 16;
    return (u16)r;
}
__device__ __forceinline__ h2_t u2h2(u32 u) {
    union { u32 a; h2_t b; } c; c.a = u; return c.b;
}
__device__ __forceinline__ u32 pk2(float a, float b) {
    union { fp16v2 v; u32 u; } c; c.v = __builtin_amdgcn_cvt_pkrtz(a, b); return c.u;
}
__device__ __forceinline__ float dot2f16(u32 w, u32 h, float acc) {
#if __has_builtin(__builtin_amdgcn_fdot2)
    return __builtin_amdgcn_fdot2(u2h2(w), u2h2(h), acc, false);
#else
    h2_t wv = u2h2(w), hv = u2h2(h);
    return acc + (float)wv.x * (float)hv.x + (float)wv.y * (float)hv.y;
#endif
}

// ---------------------------------------------------------------------------
// GEMM tile: 64x64, BK=32, 256 threads, 4x4/thread (round-9 proven).
// ---------------------------------------------------------------------------
__device__ void gemm_tile_256(const float* __restrict__ A, const int* __restrict__ gidx,
                              int lda, const float* __restrict__ Bw,
                              const float* __restrict__ bias, float* __restrict__ C,
                              int N, int K, int ldc, int bm, int bn)
{
    __shared__ float As[32][64];
    __shared__ float Bs[32][64];
    const int tid = threadIdx.x;
    const int ty = tid >> 4, tx = tid & 15;
    const int lr = tid >> 2;
    const int lk = (tid & 3) * 8;

    int am = bm + lr;
    int arow = gidx ? gidx[am] : am;
    const float* Ap = A + (size_t)arow * lda;
    int bnr = bn + lr;
    const float* Bp = (bnr < N) ? (Bw + (size_t)bnr * K) : nullptr;

    float acc[4][4] = {};

    for (int k0 = 0; k0 < K; k0 += 32) {
        int kb = k0 + lk;
        float av[8];
        if (kb + 8 <= K) {
            float4 p0 = *(const float4*)(Ap + kb);
            float4 p1 = *(const float4*)(Ap + kb + 4);
            av[0]=p0.x; av[1]=p0.y; av[2]=p0.z; av[3]=p0.w;
            av[4]=p1.x; av[5]=p1.y; av[6]=p1.z; av[7]=p1.w;
        } else {
            #pragma unroll
            for (int j = 0; j < 8; j++) av[j] = (kb + j < K) ? Ap[kb + j] : 0.0f;
        }
        #pragma unroll
        for (int j = 0; j < 8; j++) As[lk + j][lr] = av[j];
        if (Bp && kb + 8 <= K) {
            float4 p0 = *(const float4*)(Bp + kb);
            float4 p1 = *(const float4*)(Bp + kb + 4);
            av[0]=p0.x; av[1]=p0.y; av[2]=p0.z; av[3]=p0.w;
            av[4]=p1.x; av[5]=p1.y; av[6]=p1.z; av[7]=p1.w;
        } else if (Bp) {
            #pragma unroll
            for (int j = 0; j < 8; j++) av[j] = (kb + j < K) ? Bp[kb + j] : 0.0f;
        } else {
            #pragma unroll
            for (int j = 0; j < 8; j++) av[j] = 0.0f;
        }
        #pragma unroll
        for (int j = 0; j < 8; j++) Bs[lk + j][lr] = av[j];
        __syncthreads();
        #pragma unroll
        for (int kk = 0; kk < 32; kk++) {
            float4 a = *(const float4*)&As[kk][ty * 4];
            float4 b = *(const float4*)&Bs[kk][tx * 4];
            acc[0][0] += a.x*b.x; acc[0][1] += a.x*b.y; acc[0][2] += a.x*b.z; acc[0][3] += a.x*b.w;
            acc[1][0] += a.y*b.x; acc[1][1] += a.y*b.y; acc[1][2] += a.y*b.z; acc[1][3] += a.y*b.w;
            acc[2][0] += a.z*b.x; acc[2][1] += a.z*b.y; acc[2][2] += a.z*b.z; acc[2][3] += a.z*b.w;
            acc[3][0] += a.w*b.x; acc[3][1] += a.w*b.y; acc[3][2] += a.w*b.z; acc[3][3] += a.w*b.w;
        }
        __syncthreads();
    }
    #pragma unroll
    for (int i = 0; i < 4; i++) {
        int m = bm + ty * 4 + i;
        #pragma unroll
        for (int j = 0; j < 4; j++) {
            int n = bn + tx * 4 + j;
            if (n < N) C[(size_t)m * ldc + n] = acc[i][j] + bias[n];
        }
    }
}

// ---------------------------------------------------------------------------
// Kernel 1: prep v5 — xproj GEMM tiles + ALL-TILED transposes emitting
// x4-PACKED k-major layouts:
//   Wt2 :  uint4 [32][1024]   elem (i,r)  = f16 pairs kp=4i..4i+3 of Whh col r
//   Wdt :  float4[64][256]    elem (kq,h) = k=4kq..4kq+3 of Wd[h][k]
//   WoTb:  uint4 [128][500]   elem (kq,vp)= bf16 (v=2vp,2vp+1) x k=4kq..4kq+3
// ---------------------------------------------------------------------------
__global__ __launch_bounds__(256)
void prep_xproj(const float* __restrict__ emb, const int* __restrict__ tv,
                const float* __restrict__ W_ih, const float* __restrict__ b_ih,
                float* __restrict__ xproj,
                const float* __restrict__ Whh,  u32* __restrict__ Wt2,
                const float* __restrict__ Wd,   float* __restrict__ Wdt,
                const float* __restrict__ W_out, u16* __restrict__ WoTb)
{
    const int bid = blockIdx.x;
    if (bid < 128) {
        gemm_tile_256(emb, tv, E_, W_ih, b_ih, xproj, 1024, E_, 1024,
                      (bid >> 4) * 64, (bid & 15) * 64);
        return;
    }
    __shared__ float tile[64][65];
    const int tid = threadIdx.x;
    const int wv = tid >> 6;      // 0..3
    const int lane = tid & 63;

    if (bid < 192) {
        int t = bid - 128;                       // 0..63
        int r0 = (t >> 2) * 64, k0 = (t & 3) * 64;
        #pragma unroll 4
        for (int j = 0; j < 16; j++) {
            int row = wv * 16 + j;
            tile[row][lane] = Whh[(size_t)(r0 + row) * 256 + k0 + lane];
        }
        __syncthreads();
        // 32 k-pairs per tile -> 8 uint4 groups, 2 per wv
        #pragma unroll
        for (int it = 0; it < 2; it++) {
            int q = wv + 4 * it;                 // 0..7
            uint4 val;
            val.x = pk2(tile[lane][8*q + 0], tile[lane][8*q + 1]);
            val.y = pk2(tile[lane][8*q + 2], tile[lane][8*q + 3]);
            val.z = pk2(tile[lane][8*q + 4], tile[lane][8*q + 5]);
            val.w = pk2(tile[lane][8*q + 6], tile[lane][8*q + 7]);
            ((uint4*)Wt2)[(size_t)((k0 >> 3) + q) * 1024 + r0 + lane] = val;
        }
    } else if (bid < 208) {
        int t = bid - 192;                       // 0..15
        int h0 = (t >> 2) * 64, k0 = (t & 3) * 64;
        #pragma unroll 4
        for (int j = 0; j < 16; j++) {
            int row = wv * 16 + j;
            tile[row][lane] = Wd[(size_t)(h0 + row) * 256 + k0 + lane];
        }
        __syncthreads();
        // 64 k per tile -> 16 float4 groups, 4 per wv
        #pragma unroll
        for (int it = 0; it < 4; it++) {
            int q = wv + 4 * it;                 // 0..15
            float4 v;
            v.x = tile[lane][4*q + 0];
            v.y = tile[lane][4*q + 1];
            v.z = tile[lane][4*q + 2];
            v.w = tile[lane][4*q + 3];
            ((float4*)Wdt)[(size_t)((k0 >> 2) + q) * 256 + h0 + lane] = v;
        }
    } else {
        int t = bid - 208;                       // 0..127
        int v0 = (t >> 3) * 64, k0 = (t & 7) * 64;
        #pragma unroll 4
        for (int j = 0; j < 16; j++) {
            int row = wv * 16 + j;
            int v = v0 + row;
            tile[row][lane] = (v < V_) ? W_out[(size_t)v * 512 + k0 + lane] : 0.0f;
        }
        __syncthreads();
        // 64 k per tile -> 16 uint4 groups; even lanes write (v, v+1) pair
        #pragma unroll
        for (int it = 0; it < 4; it++) {
            int q = wv + 4 * it;                 // 0..15
            int v = v0 + lane;
            float a0 = tile[lane][4*q + 0], a1 = tile[lane][4*q + 1];
            float a2 = tile[lane][4*q + 2], a3 = tile[lane][4*q + 3];
            float b0 = __shfl_xor(a0, 1, 64), b1 = __shfl_xor(a1, 1, 64);
            float b2 = __shfl_xor(a2, 1, 64), b3 = __shfl_xor(a3, 1, 64);
            if (!(lane & 1) && v < V_) {
                uint4 w;
                w.x = (u32)f2bf(a0) | ((u32)f2bf(b0) << 16);
                w.y = (u32)f2bf(a1) | ((u32)f2bf(b1) << 16);
                w.z = (u32)f2bf(a2) | ((u32)f2bf(b2) << 16);
                w.w = (u32)f2bf(a3) | ((u32)f2bf(b3) << 16);
                ((uint4*)WoTb)[(size_t)((k0 >> 2) + q) * 500 + (v >> 1)] = w;
            }
        }
    }
}

// ---------------------------------------------------------------------------
// Kernel 2: lstm + enc_t, round-22 residency fix. Round-4 post-mortem:
// wreg[16] (64 VGPR) SPILLED to scratch (VGPR_Count stuck at 64, lstm
// WRITE_SIZE 8768->12736 KB = spill writes) — those groups were silently
// streaming from L2-backed scratch. Deterministic fix: wreg[8] (32 VGPR,
// total demand ~60 <= the allocator's 64 target -> cannot spill), 9 groups
// in LDS (149.5 KB of 160), 15 streamed. L2 bytes/step ~384 KB -> 240 KB.
// Accumulation order i=0..31 ascending preserved -> bit-identical.
//   bid >= 32: enc_t 128x128 tile (round-9 proven) on idle CUs.
// ---------------------------------------------------------------------------
__global__ __launch_bounds__(1024, 4)
void lstm_enct(const float* __restrict__ xproj,   // [T,B,1024]
               const u32*   __restrict__ Wt2,     // uint4 [32][1024]
               const float* __restrict__ bhh,     // [1024]
               const float* __restrict__ h0, const float* __restrict__ c0,
               float* __restrict__ combined,      // [T,B,512] second half
               float* __restrict__ hT, float* __restrict__ cT,
               const float* __restrict__ enc_raw, // [8192,256]
               const float* __restrict__ We,      // [256,256]
               const float* __restrict__ be,
               float* __restrict__ enct)          // [8192,256]
{
    const int bid = blockIdx.x;
    const int tid = threadIdx.x;
    // union'd shared: LSTM view = zs[1024] f32 | cs[256] f32 | hp[128] u32 |
    //                 wlds[9*4*1024] u32  (total 38272 words = 149.5 KB)
    //                 enc_t view = As2[32][132] | Bs2[32][132] (8448 words)
    __shared__ __align__(16) u32 smem[38272];

    if (bid < 32) {
        float* zs = (float*)smem;           // [1024]
        float* cs = (float*)(smem + 1024);  // [256]
        u32*   hp = smem + 1280;            // [128]
        u32*   wlds = smem + 1408;          // [36][1024] dword-sliced (9 groups)
        const int b = bid;
        const int r = tid;
        if (tid < 256) {
            float h0v = h0[b * 256 + tid];
            cs[tid] = c0[b * 256 + tid];
            float hpart = __shfl_xor(h0v, 1, 64);
            if (!(tid & 1)) hp[tid >> 1] = pk2(h0v, hpart);
        }
        const float bh = bhh[r];
        const uint4* wp4 = (const uint4*)Wt2 + r;

        // one-time fill: groups 24..31 -> registers (32 VGPRs, spill-proof)
        uint4 wreg[8];
        #pragma unroll
        for (int j = 0; j < 8; j++) wreg[j] = wp4[(size_t)(24 + j) * 1024];
        // one-time fill: groups 15..23 -> LDS ([dw][r]: lane stride 4B, no conflict)
        #pragma unroll
        for (int j = 0; j < 9; j++) {
            uint4 w = wp4[(size_t)(15 + j) * 1024];
            wlds[(j * 4 + 0) * 1024 + r] = w.x;
            wlds[(j * 4 + 1) * 1024 + r] = w.y;
            wlds[(j * 4 + 2) * 1024 + r] = w.z;
            wlds[(j * 4 + 3) * 1024 + r] = w.w;
        }
        __syncthreads();

        for (int t = 0; t < T_; t++) {
            float xp = xproj[((size_t)t * B_ + b) * 1024 + r];
            float acc = 0.0f;
            const uint4* hp4 = (const uint4*)hp;
            // groups 0..14: streamed from L2 (240 KB/step/block)
            #pragma unroll 5
            for (int i = 0; i < 15; i++) {
                uint4 hv = hp4[i];
                uint4 w  = wp4[(size_t)i * 1024];
                acc = dot2f16(w.x, hv.x, acc);
                acc = dot2f16(w.y, hv.y, acc);
                acc = dot2f16(w.z, hv.z, acc);
                acc = dot2f16(w.w, hv.w, acc);
            }
            // groups 15..23: LDS-resident
            #pragma unroll
            for (int j = 0; j < 9; j++) {
                uint4 hv = hp4[15 + j];
                u32 w0 = wlds[(j * 4 + 0) * 1024 + r];
                u32 w1 = wlds[(j * 4 + 1) * 1024 + r];
                u32 w2 = wlds[(j * 4 + 2) * 1024 + r];
                u32 w3 = wlds[(j * 4 + 3) * 1024 + r];
                acc = dot2f16(w0, hv.x, acc);
                acc = dot2f16(w1, hv.y, acc);
                acc = dot2f16(w2, hv.z, acc);
                acc = dot2f16(w3, hv.w, acc);
            }
            // groups 24..31: register-resident
            #pragma unroll
            for (int j = 0; j < 8; j++) {
                uint4 hv = hp4[24 + j];
                acc = dot2f16(wreg[j].x, hv.x, acc);
                acc = dot2f16(wreg[j].y, hv.y, acc);
                acc = dot2f16(wreg[j].z, hv.z, acc);
                acc = dot2f16(wreg[j].w, hv.w, acc);
            }
            zs[r] = xp + bh + acc;
            __syncthreads();

            if (tid < 256) {
                float ig = fast_sigm(zs[tid]);
                float fg = fast_sigm(zs[256 + tid]);
                float gg = fast_tanh(zs[512 + tid]);
                float og = fast_sigm(zs[768 + tid]);
                float c = fg * cs[tid] + ig * gg;
                float h = og * fast_tanh(c);
                cs[tid] = c;
                combined[((size_t)t * B_ + b) * 512 + 256 + tid] = h;
                if (t == T_ - 1) {
                    hT[b * 256 + tid] = h;
                    cT[b * 256 + tid] = c;
                }
                float hpart = __shfl_xor(h, 1, 64);
                if (!(tid & 1)) hp[tid >> 1] = pk2(h, hpart);
            }
            __syncthreads();
        }
    } else {
        float (*As2)[132] = (float (*)[132])smem;
        float (*Bs2)[132] = (float (*)[132])(smem + 4224);
        const int tile = bid - 32;
        const int bm = (tile >> 1) * 128;
        const int bn = (tile & 1) * 128;
        const int tx = tid & 31, ty = tid >> 5;
        const int lr = tid >> 3;
        const int lk = (tid & 7) * 4;

        const float* Ap = enc_raw + (size_t)(bm + lr) * 256;
        const float* Bp = We + (size_t)(bn + lr) * 256;
        float acc[4][4] = {};

        for (int k0 = 0; k0 < 256; k0 += 32) {
            float4 a4 = *(const float4*)(Ap + k0 + lk);
            float4 b4 = *(const float4*)(Bp + k0 + lk);
            As2[lk + 0][lr] = a4.x; As2[lk + 1][lr] = a4.y;
            As2[lk + 2][lr] = a4.z; As2[lk + 3][lr] = a4.w;
            Bs2[lk + 0][lr] = b4.x; Bs2[lk + 1][lr] = b4.y;
            Bs2[lk + 2][lr] = b4.z; Bs2[lk + 3][lr] = b4.w;
            __syncthreads();
            #pragma unroll
            for (int kk = 0; kk < 32; kk++) {
                float4 a = *(const float4*)&As2[kk][ty * 4];
                float4 b = *(const float4*)&Bs2[kk][tx * 4];
                acc[0][0] += a.x*b.x; acc[0][1] += a.x*b.y; acc[0][2] += a.x*b.z; acc[0][3] += a.x*b.w;
                acc[1][0] += a.y*b.x; acc[1][1] += a.y*b.y; acc[1][2] += a.y*b.z; acc[1][3] += a.y*b.w;
                acc[2][0] += a.z*b.x; acc[2][1] += a.z*b.y; acc[2][2] += a.z*b.z; acc[2][3] += a.z*b.w;
                acc[3][0] += a.w*b.x; acc[3][1] += a.w*b.y; acc[3][2] += a.w*b.z; acc[3][3] += a.w*b.w;
            }
            __syncthreads();
        }
        #pragma unroll
        for (int i = 0; i < 4; i++) {
            int m = bm + ty * 4 + i;
            #pragma unroll
            for (int j = 0; j < 4; j++) {
                int n = bn + tx * 4 + j;
                enct[(size_t)m * 256 + n] = acc[i][j] + be[n];
            }
        }
    }
}

// ---------------------------------------------------------------------------
// Kernel 3: FUSED tail — EXACT round-2 configuration (512 thr, grid 512,
// 2 blocks/CU; proven 57.8 us). Rounds 3/4 proved row-batching loses more
// to barrier serialization than it gains in L1 sharing (co-resident blocks
// already share L1 lines).
// ---------------------------------------------------------------------------
__global__ __launch_bounds__(512)
void attn_logits(const float* __restrict__ enct,        // [S,B,H]
                 const float* __restrict__ combined_in, // [T,B,512] (2nd half)
                 const float* __restrict__ Wdt,         // float4 [64][256]
                 const float* __restrict__ bd,
                 const float* __restrict__ enc_raw,     // [S,B,H]
                 const float* __restrict__ wa, const float* __restrict__ ba,
                 const int* __restrict__ lens,
                 const u16* __restrict__ WoTb,          // uint4 [128][500]
                 const float* __restrict__ b_out,       // [1000]
                 float* __restrict__ ctx_out,           // [B,T,H] (d_out)
                 float* __restrict__ probs)             // [T,B,V] (d_out)
{
    const int bid = blockIdx.x;
    const int b = bid & 31;          // XCD swizzle
    const int t = bid >> 5;
    const int tid = threadIdx.x;
    const int wv = tid >> 6, lane = tid & 63;
    __shared__ float ds[256], was[256], sc[256];
    __shared__ float crow[512];
    __shared__ float tmp2[512];
    __shared__ float lrow[1000];
    __shared__ float red[8], red2[8];

    if (tid < 256) {
        crow[256 + tid] = combined_in[((size_t)t * B_ + b) * 512 + 256 + tid];
        was[tid] = wa[tid];
    }
    const int len = lens[b];
    const float bav = ba[0];
    __syncthreads();

    {
        const int h   = tid & 255;
        const int kq0 = (tid >> 8) * 32;
        float acc = 0.0f;
        const float4* wp = (const float4*)Wdt + h;
        #pragma unroll 8
        for (int kq = kq0; kq < kq0 + 32; kq++) {
            float4 w = wp[(size_t)kq * 256];
            float4 c = *(const float4*)&crow[256 + kq * 4];
            acc += w.x * c.x;
            acc += w.y * c.y;
            acc += w.z * c.z;
            acc += w.w * c.w;
        }
        tmp2[tid] = acc;
    }
    __syncthreads();
    if (tid < 256) ds[tid] = bd[tid] + tmp2[tid] + tmp2[tid + 256];
    __syncthreads();

    for (int s = wv; s < len; s += 8) {
        const float* er = enct + ((size_t)s * B_ + b) * 256;
        float sum = 0.0f;
        #pragma unroll
        for (int j = 0; j < 4; j++) {
            int h = lane + 64 * j;
            sum += fast_tanh(er[h] + ds[h]) * was[h];
        }
        #pragma unroll
        for (int off = 32; off >= 1; off >>= 1) sum += __shfl_xor(sum, off, 64);
        if (lane == 0) sc[s] = sum + bav;
    }
    __syncthreads();

    float x = (tid < len) ? sc[tid] : -INFINITY;
    float m = x;
    #pragma unroll
    for (int off = 32; off >= 1; off >>= 1) m = fmaxf(m, __shfl_xor(m, off, 64));
    if (lane == 0) red[wv] = m;
    __syncthreads();
    m = red[0];
    #pragma unroll
    for (int i = 1; i < 8; i++) m = fmaxf(m, red[i]);
    float e = __expf(x - m);
    float ssum = e;
    #pragma unroll
    for (int off = 32; off >= 1; off >>= 1) ssum += __shfl_xor(ssum, off, 64);
    if (lane == 0) red2[wv] = ssum;
    __syncthreads();
    ssum = red2[0] + red2[1] + red2[2] + red2[3] + red2[4] + red2[5] + red2[6] + red2[7];
    if (tid < 256) sc[tid] = e / ssum;
    __syncthreads();

    {
        const int h  = tid & 255;
        const int sg = tid >> 8;
        const int mid = (len + 1) >> 1;
        const int s0 = sg ? mid : 0;
        const int s1 = sg ? len : mid;
        float cacc = 0.0f;
        const float* eb = enc_raw + (size_t)b * 256 + h;
        #pragma unroll 4
        for (int s = s0; s < s1; s++) cacc += sc[s] * eb[(size_t)s * (B_ * H_)];
        tmp2[tid] = cacc;
    }
    __syncthreads();
    if (tid < 256) {
        float ctx = tmp2[tid] + tmp2[tid + 256];
        ctx_out[((size_t)b * T_ + t) * 256 + tid] = ctx;
        crow[tid] = ctx;
    }
    __syncthreads();

    if (tid < 500) {
        const int v0 = tid * 2;
        float a0 = b_out[v0], a1 = b_out[v0 + 1];
        const uint4* wp = (const uint4*)WoTb + tid;
        #pragma unroll 8
        for (int kq = 0; kq < 128; kq++) {
            uint4 w = wp[(size_t)kq * 500];
            float4 c = *(const float4*)&crow[kq * 4];
            a0 += c.x * blo(w.x); a1 += c.x * bhi(w.x);
            a0 += c.y * blo(w.y); a1 += c.y * bhi(w.y);
            a0 += c.z * blo(w.z); a1 += c.z * bhi(w.z);
            a0 += c.w * blo(w.w); a1 += c.w * bhi(w.w);
        }
        lrow[v0] = a0;
        lrow[v0 + 1] = a1;
    }
    __syncthreads();

    float v0v = -INFINITY, v1v = -INFINITY;
    if (tid < 500) { v0v = lrow[tid * 2]; v1v = lrow[tid * 2 + 1]; }
    float mx = fmaxf(v0v, v1v);
    #pragma unroll
    for (int off = 32; off >= 1; off >>= 1) mx = fmaxf(mx, __shfl_xor(mx, off, 64));
    if (lane == 0) red[wv] = mx;
    __syncthreads();
    mx = red[0];
    #pragma unroll
    for (int i = 1; i < 8; i++) mx = fmaxf(mx, red[i]);
    float e0 = __expf(v0v - mx), e1 = __expf(v1v - mx);
    float s2 = e0 + e1;
    #pragma unroll
    for (int off = 32; off >= 1; off >>= 1) s2 += __shfl_xor(s2, off, 64);
    if (lane == 0) red2[wv] = s2;
    __syncthreads();
    s2 = red2[0] + red2[1] + red2[2] + red2[3] + red2[4] + red2[5] + red2[6] + red2[7];
    float inv = 1.0f / s2;
    if (tid < 500) {
        float2 pv = make_float2(e0 * inv, e1 * inv);
        *(float2*)&probs[((size_t)t * B_ + b) * V_ + tid * 2] = pv;
    }
}

extern "C" void kernel_launch(void* const* d_in, const int* in_sizes, int n_in,
                              void* d_out, int out_size, void* d_ws, size_t ws_size,
                              hipStream_t stream) {
    const int*   tv       = (const int*)d_in[0];
    const float* h0       = (const float*)d_in[1];
    const float* c0       = (const float*)d_in[2];
    const float* enc_raw  = (const float*)d_in[3];
    const int*   lens     = (const int*)d_in[4];
    const float* emb      = (const float*)d_in[5];
    const float* W_ih     = (const float*)d_in[6];
    const float* W_hh     = (const float*)d_in[7];
    const float* b_ih     = (const float*)d_in[8];
    const float* b_hh     = (const float*)d_in[9];
    const float* We       = (const float*)d_in[10];
    const float* be       = (const float*)d_in[11];
    const float* Wd       = (const float*)d_in[12];
    const float* bd       = (const float*)d_in[13];
    const float* wa       = (const float*)d_in[14];
    const float* ba       = (const float*)d_in[15];
    const float* W_out    = (const float*)d_in[16];
    const float* b_out    = (const float*)d_in[17];

    // workspace layout (fp32 words; round-16 proven 14.63 MB footprint)
    float* ws       = (float*)d_ws;
    float* enct     = ws;                       // [8192,256]  2,097,152
    float* xproj    = ws + 2097152;             // [512,1024]    524,288
    float* Wdt      = ws + 2621440;             // float4 [64][256]  65,536 f
    u16*   WoTb     = (u16*)(ws + 2752512);     // uint4 [128][500]  1 MB
    float* combined = ws + 3264512;             // [512,512]     262,144
    u32*   Wt2      = (u32*)(ws + 3526656);     // uint4 [32][1024]  512 KB

    // d_out layout (fp32): probs [T,B,V], hT, cT, ctx [B,T,H]
    float* out      = (float*)d_out;
    float* probs    = out;
    float* hT       = out + 512000;
    float* cT       = out + 520192;
    float* ctx_out  = out + 528384;

    // 1) xproj GEMM tiles + all-tiled coalesced transposes (x4-packed layouts)
    prep_xproj<<<336, 256, 0, stream>>>(emb, tv, W_ih, b_ih, xproj,
                                        W_hh, Wt2, Wd, Wdt, W_out, WoTb);
    // 2) LSTM (spill-proof residency: 8 reg + 9 LDS + 15 streamed groups)
    lstm_enct<<<160, 1024, 0, stream>>>(xproj, Wt2, b_hh, h0, c0, combined, hT, cT,
                                        enc_raw, We, be, enct);
    // 3) fused attention + logits + vocab softmax (exact round-2, proven)
    attn_logits<<<512, 512, 0, stream>>>(enct, combined, Wdt, bd, enc_raw,
                                         wa, ba, lens, WoTb, b_out, ctx_out, probs);
}

// Round 6
// 217.598 us; speedup vs baseline: 1.0353x; 1.0353x over previous
//
#include <hip/hip_runtime.h>
#include <hip/hip_fp16.h>
#include <math.h>

typedef unsigned int u32;
typedef unsigned short u16;

#define T_ 16
#define B_ 32
#define S_ 256
#define H_ 256
#define E_ 300
#define V_ 1000

typedef _Float16 h2_t __attribute__((ext_vector_type(2)));
typedef __fp16  fp16v2 __attribute__((ext_vector_type(2)));

__device__ __forceinline__ float fast_tanh(float x) {
    return 1.0f - 2.0f / (__expf(2.0f * x) + 1.0f);
}
__device__ __forceinline__ float fast_sigm(float x) {
    return 1.0f / (1.0f + __expf(-x));
}
__device__ __forceinline__ float bf2f(u16 x) { return __uint_as_float(((u32)x) << 16); }
__device__ __forceinline__ float blo(u32 u) { return __uint_as_float(u << 16); }
__device__ __forceinline__ float bhi(u32 u) { return __uint_as_float(u & 0xffff0000u); }
__device__ __forceinline__ u16 f2bf(float f) {
    u32 u = __float_as_uint(f);
    u32 r = (u + 0x7fffu + ((u >> 16) & 1u)) >> 16;
    return (u16)r;
}
__device__ __forceinline__ h2_t u2h2(u32 u) {
    union { u32 a; h2_t b; } c; c.a = u; return c.b;
}
__device__ __forceinline__ u32 pk2(float a, float b) {
    union { fp16v2 v; u32 u; } c; c.v = __builtin_amdgcn_cvt_pkrtz(a, b); return c.u;
}
__device__ __forceinline__ float dot2f16(u32 w, u32 h, float acc) {
#if __has_builtin(__builtin_amdgcn_fdot2)
    return __builtin_amdgcn_fdot2(u2h2(w), u2h2(h), acc, false);
#else
    h2_t wv = u2h2(w), hv = u2h2(h);
    return acc + (float)wv.x * (float)hv.x + (float)wv.y * (float)hv.y;
#endif
}

// ---------------------------------------------------------------------------
// GEMM tile: 64x64, BK=32, 256 threads, 4x4/thread (round-9 proven).
// ---------------------------------------------------------------------------
__device__ void gemm_tile_256(const float* __restrict__ A, const int* __restrict__ gidx,
                              int lda, const float* __restrict__ Bw,
                              const float* __restrict__ bias, float* __restrict__ C,
                              int N, int K, int ldc, int bm, int bn)
{
    __shared__ float As[32][64];
    __shared__ float Bs[32][64];
    const int tid = threadIdx.x;
    const int ty = tid >> 4, tx = tid & 15;
    const int lr = tid >> 2;
    const int lk = (tid & 3) * 8;

    int am = bm + lr;
    int arow = gidx ? gidx[am] : am;
    const float* Ap = A + (size_t)arow * lda;
    int bnr = bn + lr;
    const float* Bp = (bnr < N) ? (Bw + (size_t)bnr * K) : nullptr;

    float acc[4][4] = {};

    for (int k0 = 0; k0 < K; k0 += 32) {
        int kb = k0 + lk;
        float av[8];
        if (kb + 8 <= K) {
            float4 p0 = *(const float4*)(Ap + kb);
            float4 p1 = *(const float4*)(Ap + kb + 4);
            av[0]=p0.x; av[1]=p0.y; av[2]=p0.z; av[3]=p0.w;
            av[4]=p1.x; av[5]=p1.y; av[6]=p1.z; av[7]=p1.w;
        } else {
            #pragma unroll
            for (int j = 0; j < 8; j++) av[j] = (kb + j < K) ? Ap[kb + j] : 0.0f;
        }
        #pragma unroll
        for (int j = 0; j < 8; j++) As[lk + j][lr] = av[j];
        if (Bp && kb + 8 <= K) {
            float4 p0 = *(const float4*)(Bp + kb);
            float4 p1 = *(const float4*)(Bp + kb + 4);
            av[0]=p0.x; av[1]=p0.y; av[2]=p0.z; av[3]=p0.w;
            av[4]=p1.x; av[5]=p1.y; av[6]=p1.z; av[7]=p1.w;
        } else if (Bp) {
            #pragma unroll
            for (int j = 0; j < 8; j++) av[j] = (kb + j < K) ? Bp[kb + j] : 0.0f;
        } else {
            #pragma unroll
            for (int j = 0; j < 8; j++) av[j] = 0.0f;
        }
        #pragma unroll
        for (int j = 0; j < 8; j++) Bs[lk + j][lr] = av[j];
        __syncthreads();
        #pragma unroll
        for (int kk = 0; kk < 32; kk++) {
            float4 a = *(const float4*)&As[kk][ty * 4];
            float4 b = *(const float4*)&Bs[kk][tx * 4];
            acc[0][0] += a.x*b.x; acc[0][1] += a.x*b.y; acc[0][2] += a.x*b.z; acc[0][3] += a.x*b.w;
            acc[1][0] += a.y*b.x; acc[1][1] += a.y*b.y; acc[1][2] += a.y*b.z; acc[1][3] += a.y*b.w;
            acc[2][0] += a.z*b.x; acc[2][1] += a.z*b.y; acc[2][2] += a.z*b.z; acc[2][3] += a.z*b.w;
            acc[3][0] += a.w*b.x; acc[3][1] += a.w*b.y; acc[3][2] += a.w*b.z; acc[3][3] += a.w*b.w;
        }
        __syncthreads();
    }
    #pragma unroll
    for (int i = 0; i < 4; i++) {
        int m = bm + ty * 4 + i;
        #pragma unroll
        for (int j = 0; j < 4; j++) {
            int n = bn + tx * 4 + j;
            if (n < N) C[(size_t)m * ldc + n] = acc[i][j] + bias[n];
        }
    }
}

// ---------------------------------------------------------------------------
// Kernel 1: prep v5 — xproj GEMM tiles + ALL-TILED transposes emitting
// x4-PACKED k-major layouts:
//   Wt2 :  uint4 [32][1024]   elem (i,r)  = f16 pairs kp=4i..4i+3 of Whh col r
//   Wdt :  float4[64][256]    elem (kq,h) = k=4kq..4kq+3 of Wd[h][k]
//   WoTb:  uint4 [128][500]   elem (kq,vp)= bf16 (v=2vp,2vp+1) x k=4kq..4kq+3
// ---------------------------------------------------------------------------
__global__ __launch_bounds__(256)
void prep_xproj(const float* __restrict__ emb, const int* __restrict__ tv,
                const float* __restrict__ W_ih, const float* __restrict__ b_ih,
                float* __restrict__ xproj,
                const float* __restrict__ Whh,  u32* __restrict__ Wt2,
                const float* __restrict__ Wd,   float* __restrict__ Wdt,
                const float* __restrict__ W_out, u16* __restrict__ WoTb)
{
    const int bid = blockIdx.x;
    if (bid < 128) {
        gemm_tile_256(emb, tv, E_, W_ih, b_ih, xproj, 1024, E_, 1024,
                      (bid >> 4) * 64, (bid & 15) * 64);
        return;
    }
    __shared__ float tile[64][65];
    const int tid = threadIdx.x;
    const int wv = tid >> 6;      // 0..3
    const int lane = tid & 63;

    if (bid < 192) {
        int t = bid - 128;                       // 0..63
        int r0 = (t >> 2) * 64, k0 = (t & 3) * 64;
        #pragma unroll 4
        for (int j = 0; j < 16; j++) {
            int row = wv * 16 + j;
            tile[row][lane] = Whh[(size_t)(r0 + row) * 256 + k0 + lane];
        }
        __syncthreads();
        // 32 k-pairs per tile -> 8 uint4 groups, 2 per wv
        #pragma unroll
        for (int it = 0; it < 2; it++) {
            int q = wv + 4 * it;                 // 0..7
            uint4 val;
            val.x = pk2(tile[lane][8*q + 0], tile[lane][8*q + 1]);
            val.y = pk2(tile[lane][8*q + 2], tile[lane][8*q + 3]);
            val.z = pk2(tile[lane][8*q + 4], tile[lane][8*q + 5]);
            val.w = pk2(tile[lane][8*q + 6], tile[lane][8*q + 7]);
            ((uint4*)Wt2)[(size_t)((k0 >> 3) + q) * 1024 + r0 + lane] = val;
        }
    } else if (bid < 208) {
        int t = bid - 192;                       // 0..15
        int h0 = (t >> 2) * 64, k0 = (t & 3) * 64;
        #pragma unroll 4
        for (int j = 0; j < 16; j++) {
            int row = wv * 16 + j;
            tile[row][lane] = Wd[(size_t)(h0 + row) * 256 + k0 + lane];
        }
        __syncthreads();
        // 64 k per tile -> 16 float4 groups, 4 per wv
        #pragma unroll
        for (int it = 0; it < 4; it++) {
            int q = wv + 4 * it;                 // 0..15
            float4 v;
            v.x = tile[lane][4*q + 0];
            v.y = tile[lane][4*q + 1];
            v.z = tile[lane][4*q + 2];
            v.w = tile[lane][4*q + 3];
            ((float4*)Wdt)[(size_t)((k0 >> 2) + q) * 256 + h0 + lane] = v;
        }
    } else {
        int t = bid - 208;                       // 0..127
        int v0 = (t >> 3) * 64, k0 = (t & 7) * 64;
        #pragma unroll 4
        for (int j = 0; j < 16; j++) {
            int row = wv * 16 + j;
            int v = v0 + row;
            tile[row][lane] = (v < V_) ? W_out[(size_t)v * 512 + k0 + lane] : 0.0f;
        }
        __syncthreads();
        // 64 k per tile -> 16 uint4 groups; even lanes write (v, v+1) pair
        #pragma unroll
        for (int it = 0; it < 4; it++) {
            int q = wv + 4 * it;                 // 0..15
            int v = v0 + lane;
            float a0 = tile[lane][4*q + 0], a1 = tile[lane][4*q + 1];
            float a2 = tile[lane][4*q + 2], a3 = tile[lane][4*q + 3];
            float b0 = __shfl_xor(a0, 1, 64), b1 = __shfl_xor(a1, 1, 64);
            float b2 = __shfl_xor(a2, 1, 64), b3 = __shfl_xor(a3, 1, 64);
            if (!(lane & 1) && v < V_) {
                uint4 w;
                w.x = (u32)f2bf(a0) | ((u32)f2bf(b0) << 16);
                w.y = (u32)f2bf(a1) | ((u32)f2bf(b1) << 16);
                w.z = (u32)f2bf(a2) | ((u32)f2bf(b2) << 16);
                w.w = (u32)f2bf(a3) | ((u32)f2bf(b3) << 16);
                ((uint4*)WoTb)[(size_t)((k0 >> 2) + q) * 500 + (v >> 1)] = w;
            }
        }
    }
}

// ---------------------------------------------------------------------------
// Kernel 2: lstm + enc_t, round-23. Body restored to the EXACT round-2
// configuration (wreg[16] + 8 LDS groups + 8 streamed — fastest measured,
// <=57.7 us; round-5's 8/9/15 "spill-fix" split measured 61.8 -> discarded)
// with ONE change: the per-step `combined` global store is deferred into a
// 16 KB LDS buffer (hsave). The global store sat between the two barriers,
// so all 16 steps paid s_waitcnt vmcnt(0) store-retire (~200-400 cyc) on
// the recurrent critical path. LDS stores only need lgkmcnt (cheap); the
// combined/hT/cT writes happen once after the loop, coalesced. Same values,
// same addresses -> bit-identical.
//   bid >= 32: enc_t 128x128 tile (round-9 proven) on idle CUs.
// ---------------------------------------------------------------------------
__global__ __launch_bounds__(1024, 4)
void lstm_enct(const float* __restrict__ xproj,   // [T,B,1024]
               const u32*   __restrict__ Wt2,     // uint4 [32][1024]
               const float* __restrict__ bhh,     // [1024]
               const float* __restrict__ h0, const float* __restrict__ c0,
               float* __restrict__ combined,      // [T,B,512] second half
               float* __restrict__ hT, float* __restrict__ cT,
               const float* __restrict__ enc_raw, // [8192,256]
               const float* __restrict__ We,      // [256,256]
               const float* __restrict__ be,
               float* __restrict__ enct)          // [8192,256]
{
    const int bid = blockIdx.x;
    const int tid = threadIdx.x;
    // union'd shared: LSTM view = zs[1024] f32 | cs[256] f32 | hp[128] u32 |
    //                 wlds[8*4*1024] u32 | hsave[16*256] f32
    //                 (total 38272 words = 149.5 KB)
    //                 enc_t view = As2[32][132] | Bs2[32][132] (8448 words)
    __shared__ __align__(16) u32 smem[38272];

    if (bid < 32) {
        float* zs = (float*)smem;            // [1024]
        float* cs = (float*)(smem + 1024);   // [256]
        u32*   hp = smem + 1280;             // [128]
        u32*   wlds = smem + 1408;           // [32][1024] dword-sliced (8 groups)
        float* hsave = (float*)(smem + 34176); // [16][256]
        const int b = bid;
        const int r = tid;
        if (tid < 256) {
            float h0v = h0[b * 256 + tid];
            cs[tid] = c0[b * 256 + tid];
            float hpart = __shfl_xor(h0v, 1, 64);
            if (!(tid & 1)) hp[tid >> 1] = pk2(h0v, hpart);
        }
        const float bh = bhh[r];
        const uint4* wp4 = (const uint4*)Wt2 + r;

        // one-time fill: groups 16..31 -> registers (round-2 codegen)
        uint4 wreg[16];
        #pragma unroll
        for (int j = 0; j < 16; j++) wreg[j] = wp4[(size_t)(16 + j) * 1024];
        // one-time fill: groups 8..15 -> LDS ([dw][r]: lane stride 4B, no conflict)
        #pragma unroll
        for (int j = 0; j < 8; j++) {
            uint4 w = wp4[(size_t)(8 + j) * 1024];
            wlds[(j * 4 + 0) * 1024 + r] = w.x;
            wlds[(j * 4 + 1) * 1024 + r] = w.y;
            wlds[(j * 4 + 2) * 1024 + r] = w.z;
            wlds[(j * 4 + 3) * 1024 + r] = w.w;
        }
        __syncthreads();

        for (int t = 0; t < T_; t++) {
            float xp = xproj[((size_t)t * B_ + b) * 1024 + r];
            float acc = 0.0f;
            const uint4* hp4 = (const uint4*)hp;
            // groups 0..7: streamed from L2 (128 KB/step)
            #pragma unroll
            for (int i = 0; i < 8; i++) {
                uint4 hv = hp4[i];
                uint4 w  = wp4[(size_t)i * 1024];
                acc = dot2f16(w.x, hv.x, acc);
                acc = dot2f16(w.y, hv.y, acc);
                acc = dot2f16(w.z, hv.z, acc);
                acc = dot2f16(w.w, hv.w, acc);
            }
            // groups 8..15: LDS-resident
            #pragma unroll
            for (int j = 0; j < 8; j++) {
                uint4 hv = hp4[8 + j];
                u32 w0 = wlds[(j * 4 + 0) * 1024 + r];
                u32 w1 = wlds[(j * 4 + 1) * 1024 + r];
                u32 w2 = wlds[(j * 4 + 2) * 1024 + r];
                u32 w3 = wlds[(j * 4 + 3) * 1024 + r];
                acc = dot2f16(w0, hv.x, acc);
                acc = dot2f16(w1, hv.y, acc);
                acc = dot2f16(w2, hv.z, acc);
                acc = dot2f16(w3, hv.w, acc);
            }
            // groups 16..31: register-resident
            #pragma unroll
            for (int j = 0; j < 16; j++) {
                uint4 hv = hp4[16 + j];
                acc = dot2f16(wreg[j].x, hv.x, acc);
                acc = dot2f16(wreg[j].y, hv.y, acc);
                acc = dot2f16(wreg[j].z, hv.z, acc);
                acc = dot2f16(wreg[j].w, hv.w, acc);
            }
            zs[r] = xp + bh + acc;
            __syncthreads();

            if (tid < 256) {
                float ig = fast_sigm(zs[tid]);
                float fg = fast_sigm(zs[256 + tid]);
                float gg = fast_tanh(zs[512 + tid]);
                float og = fast_sigm(zs[768 + tid]);
                float c = fg * cs[tid] + ig * gg;
                float h = og * fast_tanh(c);
                cs[tid] = c;
                hsave[(t << 8) + tid] = h;       // LDS, no vmcnt drain
                float hpart = __shfl_xor(h, 1, 64);
                if (!(tid & 1)) hp[tid >> 1] = pk2(h, hpart);
            }
            __syncthreads();
        }

        // deferred global writes: coalesced, once
        #pragma unroll
        for (int i = 0; i < 4; i++) {
            int idx = tid + i * 1024;            // 0..4095
            int t = idx >> 8, h = idx & 255;
            combined[((size_t)t * B_ + b) * 512 + 256 + h] = hsave[idx];
        }
        if (tid < 256) {
            hT[b * 256 + tid] = hsave[(15 << 8) + tid];
            cT[b * 256 + tid] = cs[tid];
        }
    } else {
        float (*As2)[132] = (float (*)[132])smem;
        float (*Bs2)[132] = (float (*)[132])(smem + 4224);
        const int tile = bid - 32;
        const int bm = (tile >> 1) * 128;
        const int bn = (tile & 1) * 128;
        const int tx = tid & 31, ty = tid >> 5;
        const int lr = tid >> 3;
        const int lk = (tid & 7) * 4;

        const float* Ap = enc_raw + (size_t)(bm + lr) * 256;
        const float* Bp = We + (size_t)(bn + lr) * 256;
        float acc[4][4] = {};

        for (int k0 = 0; k0 < 256; k0 += 32) {
            float4 a4 = *(const float4*)(Ap + k0 + lk);
            float4 b4 = *(const float4*)(Bp + k0 + lk);
            As2[lk + 0][lr] = a4.x; As2[lk + 1][lr] = a4.y;
            As2[lk + 2][lr] = a4.z; As2[lk + 3][lr] = a4.w;
            Bs2[lk + 0][lr] = b4.x; Bs2[lk + 1][lr] = b4.y;
            Bs2[lk + 2][lr] = b4.z; Bs2[lk + 3][lr] = b4.w;
            __syncthreads();
            #pragma unroll
            for (int kk = 0; kk < 32; kk++) {
                float4 a = *(const float4*)&As2[kk][ty * 4];
                float4 b = *(const float4*)&Bs2[kk][tx * 4];
                acc[0][0] += a.x*b.x; acc[0][1] += a.x*b.y; acc[0][2] += a.x*b.z; acc[0][3] += a.x*b.w;
                acc[1][0] += a.y*b.x; acc[1][1] += a.y*b.y; acc[1][2] += a.y*b.z; acc[1][3] += a.y*b.w;
                acc[2][0] += a.z*b.x; acc[2][1] += a.z*b.y; acc[2][2] += a.z*b.z; acc[2][3] += a.z*b.w;
                acc[3][0] += a.w*b.x; acc[3][1] += a.w*b.y; acc[3][2] += a.w*b.z; acc[3][3] += a.w*b.w;
            }
            __syncthreads();
        }
        #pragma unroll
        for (int i = 0; i < 4; i++) {
            int m = bm + ty * 4 + i;
            #pragma unroll
            for (int j = 0; j < 4; j++) {
                int n = bn + tx * 4 + j;
                enct[(size_t)m * 256 + n] = acc[i][j] + be[n];
            }
        }
    }
}

// ---------------------------------------------------------------------------
// Kernel 3: FUSED tail — EXACT round-2 configuration (512 thr, grid 512,
// 2 blocks/CU; proven 57.8 us). Rounds 3/4 proved row-batching loses more
// to barrier serialization than it gains in L1 sharing.
// ---------------------------------------------------------------------------
__global__ __launch_bounds__(512)
void attn_logits(const float* __restrict__ enct,        // [S,B,H]
                 const float* __restrict__ combined_in, // [T,B,512] (2nd half)
                 const float* __restrict__ Wdt,         // float4 [64][256]
                 const float* __restrict__ bd,
                 const float* __restrict__ enc_raw,     // [S,B,H]
                 const float* __restrict__ wa, const float* __restrict__ ba,
                 const int* __restrict__ lens,
                 const u16* __restrict__ WoTb,          // uint4 [128][500]
                 const float* __restrict__ b_out,       // [1000]
                 float* __restrict__ ctx_out,           // [B,T,H] (d_out)
                 float* __restrict__ probs)             // [T,B,V] (d_out)
{
    const int bid = blockIdx.x;
    const int b = bid & 31;          // XCD swizzle
    const int t = bid >> 5;
    const int tid = threadIdx.x;
    const int wv = tid >> 6, lane = tid & 63;
    __shared__ float ds[256], was[256], sc[256];
    __shared__ float crow[512];
    __shared__ float tmp2[512];
    __shared__ float lrow[1000];
    __shared__ float red[8], red2[8];

    if (tid < 256) {
        crow[256 + tid] = combined_in[((size_t)t * B_ + b) * 512 + 256 + tid];
        was[tid] = wa[tid];
    }
    const int len = lens[b];
    const float bav = ba[0];
    __syncthreads();

    {
        const int h   = tid & 255;
        const int kq0 = (tid >> 8) * 32;
        float acc = 0.0f;
        const float4* wp = (const float4*)Wdt + h;
        #pragma unroll 8
        for (int kq = kq0; kq < kq0 + 32; kq++) {
            float4 w = wp[(size_t)kq * 256];
            float4 c = *(const float4*)&crow[256 + kq * 4];
            acc += w.x * c.x;
            acc += w.y * c.y;
            acc += w.z * c.z;
            acc += w.w * c.w;
        }
        tmp2[tid] = acc;
    }
    __syncthreads();
    if (tid < 256) ds[tid] = bd[tid] + tmp2[tid] + tmp2[tid + 256];
    __syncthreads();

    for (int s = wv; s < len; s += 8) {
        const float* er = enct + ((size_t)s * B_ + b) * 256;
        float sum = 0.0f;
        #pragma unroll
        for (int j = 0; j < 4; j++) {
            int h = lane + 64 * j;
            sum += fast_tanh(er[h] + ds[h]) * was[h];
        }
        #pragma unroll
        for (int off = 32; off >= 1; off >>= 1) sum += __shfl_xor(sum, off, 64);
        if (lane == 0) sc[s] = sum + bav;
    }
    __syncthreads();

    float x = (tid < len) ? sc[tid] : -INFINITY;
    float m = x;
    #pragma unroll
    for (int off = 32; off >= 1; off >>= 1) m = fmaxf(m, __shfl_xor(m, off, 64));
    if (lane == 0) red[wv] = m;
    __syncthreads();
    m = red[0];
    #pragma unroll
    for (int i = 1; i < 8; i++) m = fmaxf(m, red[i]);
    float e = __expf(x - m);
    float ssum = e;
    #pragma unroll
    for (int off = 32; off >= 1; off >>= 1) ssum += __shfl_xor(ssum, off, 64);
    if (lane == 0) red2[wv] = ssum;
    __syncthreads();
    ssum = red2[0] + red2[1] + red2[2] + red2[3] + red2[4] + red2[5] + red2[6] + red2[7];
    if (tid < 256) sc[tid] = e / ssum;
    __syncthreads();

    {
        const int h  = tid & 255;
        const int sg = tid >> 8;
        const int mid = (len + 1) >> 1;
        const int s0 = sg ? mid : 0;
        const int s1 = sg ? len : mid;
        float cacc = 0.0f;
        const float* eb = enc_raw + (size_t)b * 256 + h;
        #pragma unroll 4
        for (int s = s0; s < s1; s++) cacc += sc[s] * eb[(size_t)s * (B_ * H_)];
        tmp2[tid] = cacc;
    }
    __syncthreads();
    if (tid < 256) {
        float ctx = tmp2[tid] + tmp2[tid + 256];
        ctx_out[((size_t)b * T_ + t) * 256 + tid] = ctx;
        crow[tid] = ctx;
    }
    __syncthreads();

    if (tid < 500) {
        const int v0 = tid * 2;
        float a0 = b_out[v0], a1 = b_out[v0 + 1];
        const uint4* wp = (const uint4*)WoTb + tid;
        #pragma unroll 8
        for (int kq = 0; kq < 128; kq++) {
            uint4 w = wp[(size_t)kq * 500];
            float4 c = *(const float4*)&crow[kq * 4];
            a0 += c.x * blo(w.x); a1 += c.x * bhi(w.x);
            a0 += c.y * blo(w.y); a1 += c.y * bhi(w.y);
            a0 += c.z * blo(w.z); a1 += c.z * bhi(w.z);
            a0 += c.w * blo(w.w); a1 += c.w * bhi(w.w);
        }
        lrow[v0] = a0;
        lrow[v0 + 1] = a1;
    }
    __syncthreads();

    float v0v = -INFINITY, v1v = -INFINITY;
    if (tid < 500) { v0v = lrow[tid * 2]; v1v = lrow[tid * 2 + 1]; }
    float mx = fmaxf(v0v, v1v);
    #pragma unroll
    for (int off = 32; off >= 1; off >>= 1) mx = fmaxf(mx, __shfl_xor(mx, off, 64));
    if (lane == 0) red[wv] = mx;
    __syncthreads();
    mx = red[0];
    #pragma unroll
    for (int i = 1; i < 8; i++) mx = fmaxf(mx, red[i]);
    float e0 = __expf(v0v - mx), e1 = __expf(v1v - mx);
    float s2 = e0 + e1;
    #pragma unroll
    for (int off = 32; off >= 1; off >>= 1) s2 += __shfl_xor(s2, off, 64);
    if (lane == 0) red2[wv] = s2;
    __syncthreads();
    s2 = red2[0] + red2[1] + red2[2] + red2[3] + red2[4] + red2[5] + red2[6] + red2[7];
    float inv = 1.0f / s2;
    if (tid < 500) {
        float2 pv = make_float2(e0 * inv, e1 * inv);
        *(float2*)&probs[((size_t)t * B_ + b) * V_ + tid * 2] = pv;
    }
}

extern "C" void kernel_launch(void* const* d_in, const int* in_sizes, int n_in,
                              void* d_out, int out_size, void* d_ws, size_t ws_size,
                              hipStream_t stream) {
    const int*   tv       = (const int*)d_in[0];
    const float* h0       = (const float*)d_in[1];
    const float* c0       = (const float*)d_in[2];
    const float* enc_raw  = (const float*)d_in[3];
    const int*   lens     = (const int*)d_in[4];
    const float* emb      = (const float*)d_in[5];
    const float* W_ih     = (const float*)d_in[6];
    const float* W_hh     = (const float*)d_in[7];
    const float* b_ih     = (const float*)d_in[8];
    const float* b_hh     = (const float*)d_in[9];
    const float* We       = (const float*)d_in[10];
    const float* be       = (const float*)d_in[11];
    const float* Wd       = (const float*)d_in[12];
    const float* bd       = (const float*)d_in[13];
    const float* wa       = (const float*)d_in[14];
    const float* ba       = (const float*)d_in[15];
    const float* W_out    = (const float*)d_in[16];
    const float* b_out    = (const float*)d_in[17];

    // workspace layout (fp32 words; round-16 proven 14.63 MB footprint)
    float* ws       = (float*)d_ws;
    float* enct     = ws;                       // [8192,256]  2,097,152
    float* xproj    = ws + 2097152;             // [512,1024]    524,288
    float* Wdt      = ws + 2621440;             // float4 [64][256]  65,536 f
    u16*   WoTb     = (u16*)(ws + 2752512);     // uint4 [128][500]  1 MB
    float* combined = ws + 3264512;             // [512,512]     262,144
    u32*   Wt2      = (u32*)(ws + 3526656);     // uint4 [32][1024]  512 KB

    // d_out layout (fp32): probs [T,B,V], hT, cT, ctx [B,T,H]
    float* out      = (float*)d_out;
    float* probs    = out;
    float* hT       = out + 512000;
    float* cT       = out + 520192;
    float* ctx_out  = out + 528384;

    // 1) xproj GEMM tiles + all-tiled coalesced transposes (x4-packed layouts)
    prep_xproj<<<336, 256, 0, stream>>>(emb, tv, W_ih, b_ih, xproj,
                                        W_hh, Wt2, Wd, Wdt, W_out, WoTb);
    // 2) LSTM (round-2 residency, deferred combined/hT/cT stores) + enc_t
    lstm_enct<<<160, 1024, 0, stream>>>(xproj, Wt2, b_hh, h0, c0, combined, hT, cT,
                                        enc_raw, We, be, enct);
    // 3) fused attention + logits + vocab softmax (exact round-2, proven)
    attn_logits<<<512, 512, 0, stream>>>(enct, combined, Wdt, bd, enc_raw,
                                         wa, ba, lens, WoTb, b_out, ctx_out, probs);
}

// Round 7
// 208.709 us; speedup vs baseline: 1.0794x; 1.0426x over previous
//
#include <hip/hip_runtime.h>
#include <hip/hip_fp16.h>
#include <math.h>

typedef unsigned int u32;
typedef unsigned short u16;

#define T_ 16
#define B_ 32
#define S_ 256
#define H_ 256
#define E_ 300
#define V_ 1000

typedef _Float16 h2_t __attribute__((ext_vector_type(2)));
typedef __fp16  fp16v2 __attribute__((ext_vector_type(2)));

__device__ __forceinline__ float fast_tanh(float x) {
    return 1.0f - 2.0f / (__expf(2.0f * x) + 1.0f);
}
__device__ __forceinline__ float fast_sigm(float x) {
    return 1.0f / (1.0f + __expf(-x));
}
__device__ __forceinline__ float bf2f(u16 x) { return __uint_as_float(((u32)x) << 16); }
__device__ __forceinline__ float blo(u32 u) { return __uint_as_float(u << 16); }
__device__ __forceinline__ float bhi(u32 u) { return __uint_as_float(u & 0xffff0000u); }
__device__ __forceinline__ u16 f2bf(float f) {
    u32 u = __float_as_uint(f);
    u32 r = (u + 0x7fffu + ((u >> 16) & 1u)) >> 16;
    return (u16)r;
}
__device__ __forceinline__ h2_t u2h2(u32 u) {
    union { u32 a; h2_t b; } c; c.a = u; return c.b;
}
__device__ __forceinline__ u32 pk2(float a, float b) {
    union { fp16v2 v; u32 u; } c; c.v = __builtin_amdgcn_cvt_pkrtz(a, b); return c.u;
}
__device__ __forceinline__ float dot2f16(u32 w, u32 h, float acc) {
#if __has_builtin(__builtin_amdgcn_fdot2)
    return __builtin_amdgcn_fdot2(u2h2(w), u2h2(h), acc, false);
#else
    h2_t wv = u2h2(w), hv = u2h2(h);
    return acc + (float)wv.x * (float)hv.x + (float)wv.y * (float)hv.y;
#endif
}

// ---------------------------------------------------------------------------
// Kernel 1: prep v6 — xproj GEMM re-tiled 32x64 (grid 256, 4 waves/CU vs the
// old 64x64's 2 — the GEMM was latency-bound at 2 waves/CU) + Whh transpose.
// Per-output k-accumulation order identical to the old tile (k ascending,
// same FMA sequence) -> bit-identical xproj. Wd/W_out transposes moved to
// lstm_enct (idle-CU work there).
// ---------------------------------------------------------------------------
__global__ __launch_bounds__(256)
void prep_xproj(const float* __restrict__ emb, const int* __restrict__ tv,
                const float* __restrict__ W_ih, const float* __restrict__ b_ih,
                float* __restrict__ xproj,
                const float* __restrict__ Whh,  u32* __restrict__ Wt2)
{
    const int bid = blockIdx.x;
    const int tid = threadIdx.x;
    if (bid < 256) {
        // 32x64 tile: bm = (bid>>4)*32, bn = (bid&15)*64, K=300
        __shared__ float As[32][33];
        __shared__ float Bs[32][64];
        const int bm = (bid >> 4) * 32;
        const int bn = (bid & 15) * 64;
        const int ty = tid >> 4;        // 0..15 -> 2 rows
        const int tx = tid & 15;        // 0..15 -> 4 cols
        const int alr = tid >> 3;       // 0..31 (A row)
        const int alk = (tid & 7) * 4;  // A k-offset
        const int blr = tid >> 2;       // 0..63 (B row)
        const int blk = (tid & 3) * 8;  // B k-offset

        const float* Ap = emb + (size_t)tv[bm + alr] * E_;
        const float* Bp = W_ih + (size_t)(bn + blr) * E_;

        float acc[2][4] = {};
        for (int k0 = 0; k0 < E_; k0 += 32) {
            int kb = k0 + alk;
            float4 a4;
            if (kb + 4 <= E_) {
                a4 = *(const float4*)(Ap + kb);
            } else {
                a4.x = (kb + 0 < E_) ? Ap[kb + 0] : 0.0f;
                a4.y = (kb + 1 < E_) ? Ap[kb + 1] : 0.0f;
                a4.z = (kb + 2 < E_) ? Ap[kb + 2] : 0.0f;
                a4.w = (kb + 3 < E_) ? Ap[kb + 3] : 0.0f;
            }
            As[alk + 0][alr] = a4.x; As[alk + 1][alr] = a4.y;
            As[alk + 2][alr] = a4.z; As[alk + 3][alr] = a4.w;

            int kbb = k0 + blk;
            float bv[8];
            if (kbb + 8 <= E_) {
                float4 p0 = *(const float4*)(Bp + kbb);
                float4 p1 = *(const float4*)(Bp + kbb + 4);
                bv[0]=p0.x; bv[1]=p0.y; bv[2]=p0.z; bv[3]=p0.w;
                bv[4]=p1.x; bv[5]=p1.y; bv[6]=p1.z; bv[7]=p1.w;
            } else {
                #pragma unroll
                for (int j = 0; j < 8; j++) bv[j] = (kbb + j < E_) ? Bp[kbb + j] : 0.0f;
            }
            #pragma unroll
            for (int j = 0; j < 8; j++) Bs[blk + j][blr] = bv[j];
            __syncthreads();
            #pragma unroll
            for (int kk = 0; kk < 32; kk++) {
                float ax = As[kk][ty * 2], ay = As[kk][ty * 2 + 1];
                float4 b = *(const float4*)&Bs[kk][tx * 4];
                acc[0][0] += ax*b.x; acc[0][1] += ax*b.y; acc[0][2] += ax*b.z; acc[0][3] += ax*b.w;
                acc[1][0] += ay*b.x; acc[1][1] += ay*b.y; acc[1][2] += ay*b.z; acc[1][3] += ay*b.w;
            }
            __syncthreads();
        }
        #pragma unroll
        for (int i = 0; i < 2; i++) {
            int m = bm + ty * 2 + i;
            #pragma unroll
            for (int j = 0; j < 4; j++) {
                int n = bn + tx * 4 + j;
                xproj[(size_t)m * 1024 + n] = acc[i][j] + b_ih[n];
            }
        }
        return;
    }
    // Whh transpose -> Wt2 uint4 [32][1024] (f16 pairs), bids 256..319
    __shared__ float tile[64][65];
    const int wv = tid >> 6;      // 0..3
    const int lane = tid & 63;
    int t = bid - 256;                       // 0..63
    int r0 = (t >> 2) * 64, k0 = (t & 3) * 64;
    #pragma unroll 4
    for (int j = 0; j < 16; j++) {
        int row = wv * 16 + j;
        tile[row][lane] = Whh[(size_t)(r0 + row) * 256 + k0 + lane];
    }
    __syncthreads();
    #pragma unroll
    for (int it = 0; it < 2; it++) {
        int q = wv + 4 * it;                 // 0..7
        uint4 val;
        val.x = pk2(tile[lane][8*q + 0], tile[lane][8*q + 1]);
        val.y = pk2(tile[lane][8*q + 2], tile[lane][8*q + 3]);
        val.z = pk2(tile[lane][8*q + 4], tile[lane][8*q + 5]);
        val.w = pk2(tile[lane][8*q + 6], tile[lane][8*q + 7]);
        ((uint4*)Wt2)[(size_t)((k0 >> 3) + q) * 1024 + r0 + lane] = val;
    }
}

// ---------------------------------------------------------------------------
// Kernel 2: lstm + enc_t + Wd/Wout transposes. Round-24 key change:
// amdgpu_waves_per_eu(4,4). Every prior round shows VGPR_Count=64 with
// wreg[16] needing ~100 regs -> the allocator targeted 8 waves/EU and
// SPILLED the weight array to scratch (WRITE_SIZE 8768->12736 KB = spill).
// LDS (149.5 KB -> 1 block/CU = 16 waves = 4/EU) already caps occupancy at
// 4 waves/EU, so the 8-wave register target bought nothing. Pinning 4,4
// raises the VGPR budget to 128 and puts wreg[16] in actual registers.
// Body otherwise byte-identical to round 6 (hsave defer kept).
//   bid 32..159 : enc_t 128x128 tile (round-9 proven)
//   bid 160..175: Wd transpose    (moved from prep; idle-CU work)
//   bid 176..303: W_out transpose (moved from prep; idle-CU work)
// ---------------------------------------------------------------------------
__global__ __launch_bounds__(1024)
__attribute__((amdgpu_waves_per_eu(4, 4)))
void lstm_enct(const float* __restrict__ xproj,   // [T,B,1024]
               const u32*   __restrict__ Wt2,     // uint4 [32][1024]
               const float* __restrict__ bhh,     // [1024]
               const float* __restrict__ h0, const float* __restrict__ c0,
               float* __restrict__ combined,      // [T,B,512] second half
               float* __restrict__ hT, float* __restrict__ cT,
               const float* __restrict__ enc_raw, // [8192,256]
               const float* __restrict__ We,      // [256,256]
               const float* __restrict__ be,
               float* __restrict__ enct,          // [8192,256]
               const float* __restrict__ Wd,   float* __restrict__ Wdt,
               const float* __restrict__ W_out, u16* __restrict__ WoTb)
{
    const int bid = blockIdx.x;
    const int tid = threadIdx.x;
    // union'd shared: LSTM view = zs[1024] f32 | cs[256] f32 | hp[128] u32 |
    //                 wlds[8*4*1024] u32 | hsave[16*256] f32  (149.5 KB)
    //                 enc_t view = As2[32][132] | Bs2[32][132]
    //                 transpose view = tile[64][65]
    __shared__ __align__(16) u32 smem[38272];

    if (bid < 32) {
        float* zs = (float*)smem;            // [1024]
        float* cs = (float*)(smem + 1024);   // [256]
        u32*   hp = smem + 1280;             // [128]
        u32*   wlds = smem + 1408;           // [32][1024] dword-sliced (8 groups)
        float* hsave = (float*)(smem + 34176); // [16][256]
        const int b = bid;
        const int r = tid;
        if (tid < 256) {
            float h0v = h0[b * 256 + tid];
            cs[tid] = c0[b * 256 + tid];
            float hpart = __shfl_xor(h0v, 1, 64);
            if (!(tid & 1)) hp[tid >> 1] = pk2(h0v, hpart);
        }
        const float bh = bhh[r];
        const uint4* wp4 = (const uint4*)Wt2 + r;

        // one-time fill: groups 16..31 -> registers (64 VGPRs, now unspilled)
        uint4 wreg[16];
        #pragma unroll
        for (int j = 0; j < 16; j++) wreg[j] = wp4[(size_t)(16 + j) * 1024];
        // one-time fill: groups 8..15 -> LDS ([dw][r]: lane stride 4B, no conflict)
        #pragma unroll
        for (int j = 0; j < 8; j++) {
            uint4 w = wp4[(size_t)(8 + j) * 1024];
            wlds[(j * 4 + 0) * 1024 + r] = w.x;
            wlds[(j * 4 + 1) * 1024 + r] = w.y;
            wlds[(j * 4 + 2) * 1024 + r] = w.z;
            wlds[(j * 4 + 3) * 1024 + r] = w.w;
        }
        __syncthreads();

        for (int t = 0; t < T_; t++) {
            float xp = xproj[((size_t)t * B_ + b) * 1024 + r];
            float acc = 0.0f;
            const uint4* hp4 = (const uint4*)hp;
            // groups 0..7: streamed from L2 (128 KB/step)
            #pragma unroll
            for (int i = 0; i < 8; i++) {
                uint4 hv = hp4[i];
                uint4 w  = wp4[(size_t)i * 1024];
                acc = dot2f16(w.x, hv.x, acc);
                acc = dot2f16(w.y, hv.y, acc);
                acc = dot2f16(w.z, hv.z, acc);
                acc = dot2f16(w.w, hv.w, acc);
            }
            // groups 8..15: LDS-resident
            #pragma unroll
            for (int j = 0; j < 8; j++) {
                uint4 hv = hp4[8 + j];
                u32 w0 = wlds[(j * 4 + 0) * 1024 + r];
                u32 w1 = wlds[(j * 4 + 1) * 1024 + r];
                u32 w2 = wlds[(j * 4 + 2) * 1024 + r];
                u32 w3 = wlds[(j * 4 + 3) * 1024 + r];
                acc = dot2f16(w0, hv.x, acc);
                acc = dot2f16(w1, hv.y, acc);
                acc = dot2f16(w2, hv.z, acc);
                acc = dot2f16(w3, hv.w, acc);
            }
            // groups 16..31: register-resident
            #pragma unroll
            for (int j = 0; j < 16; j++) {
                uint4 hv = hp4[16 + j];
                acc = dot2f16(wreg[j].x, hv.x, acc);
                acc = dot2f16(wreg[j].y, hv.y, acc);
                acc = dot2f16(wreg[j].z, hv.z, acc);
                acc = dot2f16(wreg[j].w, hv.w, acc);
            }
            zs[r] = xp + bh + acc;
            __syncthreads();

            if (tid < 256) {
                float ig = fast_sigm(zs[tid]);
                float fg = fast_sigm(zs[256 + tid]);
                float gg = fast_tanh(zs[512 + tid]);
                float og = fast_sigm(zs[768 + tid]);
                float c = fg * cs[tid] + ig * gg;
                float h = og * fast_tanh(c);
                cs[tid] = c;
                hsave[(t << 8) + tid] = h;       // LDS, no vmcnt drain
                float hpart = __shfl_xor(h, 1, 64);
                if (!(tid & 1)) hp[tid >> 1] = pk2(h, hpart);
            }
            __syncthreads();
        }

        // deferred global writes: coalesced, once
        #pragma unroll
        for (int i = 0; i < 4; i++) {
            int idx = tid + i * 1024;            // 0..4095
            int t = idx >> 8, h = idx & 255;
            combined[((size_t)t * B_ + b) * 512 + 256 + h] = hsave[idx];
        }
        if (tid < 256) {
            hT[b * 256 + tid] = hsave[(15 << 8) + tid];
            cT[b * 256 + tid] = cs[tid];
        }
    } else if (bid < 160) {
        float (*As2)[132] = (float (*)[132])smem;
        float (*Bs2)[132] = (float (*)[132])(smem + 4224);
        const int tile = bid - 32;
        const int bm = (tile >> 1) * 128;
        const int bn = (tile & 1) * 128;
        const int tx = tid & 31, ty = tid >> 5;
        const int lr = tid >> 3;
        const int lk = (tid & 7) * 4;

        const float* Ap = enc_raw + (size_t)(bm + lr) * 256;
        const float* Bp = We + (size_t)(bn + lr) * 256;
        float acc[4][4] = {};

        for (int k0 = 0; k0 < 256; k0 += 32) {
            float4 a4 = *(const float4*)(Ap + k0 + lk);
            float4 b4 = *(const float4*)(Bp + k0 + lk);
            As2[lk + 0][lr] = a4.x; As2[lk + 1][lr] = a4.y;
            As2[lk + 2][lr] = a4.z; As2[lk + 3][lr] = a4.w;
            Bs2[lk + 0][lr] = b4.x; Bs2[lk + 1][lr] = b4.y;
            Bs2[lk + 2][lr] = b4.z; Bs2[lk + 3][lr] = b4.w;
            __syncthreads();
            #pragma unroll
            for (int kk = 0; kk < 32; kk++) {
                float4 a = *(const float4*)&As2[kk][ty * 4];
                float4 b = *(const float4*)&Bs2[kk][tx * 4];
                acc[0][0] += a.x*b.x; acc[0][1] += a.x*b.y; acc[0][2] += a.x*b.z; acc[0][3] += a.x*b.w;
                acc[1][0] += a.y*b.x; acc[1][1] += a.y*b.y; acc[1][2] += a.y*b.z; acc[1][3] += a.y*b.w;
                acc[2][0] += a.z*b.x; acc[2][1] += a.z*b.y; acc[2][2] += a.z*b.z; acc[2][3] += a.z*b.w;
                acc[3][0] += a.w*b.x; acc[3][1] += a.w*b.y; acc[3][2] += a.w*b.z; acc[3][3] += a.w*b.w;
            }
            __syncthreads();
        }
        #pragma unroll
        for (int i = 0; i < 4; i++) {
            int m = bm + ty * 4 + i;
            #pragma unroll
            for (int j = 0; j < 4; j++) {
                int n = bn + tx * 4 + j;
                enct[(size_t)m * 256 + n] = acc[i][j] + be[n];
            }
        }
    } else if (bid < 176) {
        // Wd transpose (moved from prep): 16 tiles of 64x64, 1024 threads
        float (*tile)[65] = (float (*)[65])smem;
        const int w = tid >> 6;        // 0..15
        const int lane = tid & 63;
        int t = bid - 160;             // 0..15
        int h0 = (t >> 2) * 64, k0 = (t & 3) * 64;
        #pragma unroll
        for (int j = 0; j < 4; j++) {
            int row = w * 4 + j;
            tile[row][lane] = Wd[(size_t)(h0 + row) * 256 + k0 + lane];
        }
        __syncthreads();
        {
            int q = w;                 // 0..15
            float4 v;
            v.x = tile[lane][4*q + 0];
            v.y = tile[lane][4*q + 1];
            v.z = tile[lane][4*q + 2];
            v.w = tile[lane][4*q + 3];
            ((float4*)Wdt)[(size_t)((k0 >> 2) + q) * 256 + h0 + lane] = v;
        }
    } else {
        // W_out transpose (moved from prep): 128 tiles, 1024 threads
        float (*tile)[65] = (float (*)[65])smem;
        const int w = tid >> 6;        // 0..15
        const int lane = tid & 63;
        int t = bid - 176;             // 0..127
        int v0 = (t >> 3) * 64, k0 = (t & 7) * 64;
        #pragma unroll
        for (int j = 0; j < 4; j++) {
            int row = w * 4 + j;
            int v = v0 + row;
            tile[row][lane] = (v < V_) ? W_out[(size_t)v * 512 + k0 + lane] : 0.0f;
        }
        __syncthreads();
        {
            int q = w;                 // 0..15
            int v = v0 + lane;
            float a0 = tile[lane][4*q + 0], a1 = tile[lane][4*q + 1];
            float a2 = tile[lane][4*q + 2], a3 = tile[lane][4*q + 3];
            float b0 = __shfl_xor(a0, 1, 64), b1 = __shfl_xor(a1, 1, 64);
            float b2 = __shfl_xor(a2, 1, 64), b3 = __shfl_xor(a3, 1, 64);
            if (!(lane & 1) && v < V_) {
                uint4 wq;
                wq.x = (u32)f2bf(a0) | ((u32)f2bf(b0) << 16);
                wq.y = (u32)f2bf(a1) | ((u32)f2bf(b1) << 16);
                wq.z = (u32)f2bf(a2) | ((u32)f2bf(b2) << 16);
                wq.w = (u32)f2bf(a3) | ((u32)f2bf(b3) << 16);
                ((uint4*)WoTb)[(size_t)((k0 >> 2) + q) * 500 + (v >> 1)] = wq;
            }
        }
    }
}

// ---------------------------------------------------------------------------
// Kernel 3: FUSED tail — EXACT round-2 configuration (512 thr, grid 512,
// 2 blocks/CU; proven 57.5-58 us across four rounds). Rounds 3/4 proved
// row-batching loses more to barrier serialization than it gains in L1
// sharing.
// ---------------------------------------------------------------------------
__global__ __launch_bounds__(512)
void attn_logits(const float* __restrict__ enct,        // [S,B,H]
                 const float* __restrict__ combined_in, // [T,B,512] (2nd half)
                 const float* __restrict__ Wdt,         // float4 [64][256]
                 const float* __restrict__ bd,
                 const float* __restrict__ enc_raw,     // [S,B,H]
                 const float* __restrict__ wa, const float* __restrict__ ba,
                 const int* __restrict__ lens,
                 const u16* __restrict__ WoTb,          // uint4 [128][500]
                 const float* __restrict__ b_out,       // [1000]
                 float* __restrict__ ctx_out,           // [B,T,H] (d_out)
                 float* __restrict__ probs)             // [T,B,V] (d_out)
{
    const int bid = blockIdx.x;
    const int b = bid & 31;          // XCD swizzle
    const int t = bid >> 5;
    const int tid = threadIdx.x;
    const int wv = tid >> 6, lane = tid & 63;
    __shared__ float ds[256], was[256], sc[256];
    __shared__ float crow[512];
    __shared__ float tmp2[512];
    __shared__ float lrow[1000];
    __shared__ float red[8], red2[8];

    if (tid < 256) {
        crow[256 + tid] = combined_in[((size_t)t * B_ + b) * 512 + 256 + tid];
        was[tid] = wa[tid];
    }
    const int len = lens[b];
    const float bav = ba[0];
    __syncthreads();

    {
        const int h   = tid & 255;
        const int kq0 = (tid >> 8) * 32;
        float acc = 0.0f;
        const float4* wp = (const float4*)Wdt + h;
        #pragma unroll 8
        for (int kq = kq0; kq < kq0 + 32; kq++) {
            float4 w = wp[(size_t)kq * 256];
            float4 c = *(const float4*)&crow[256 + kq * 4];
            acc += w.x * c.x;
            acc += w.y * c.y;
            acc += w.z * c.z;
            acc += w.w * c.w;
        }
        tmp2[tid] = acc;
    }
    __syncthreads();
    if (tid < 256) ds[tid] = bd[tid] + tmp2[tid] + tmp2[tid + 256];
    __syncthreads();

    for (int s = wv; s < len; s += 8) {
        const float* er = enct + ((size_t)s * B_ + b) * 256;
        float sum = 0.0f;
        #pragma unroll
        for (int j = 0; j < 4; j++) {
            int h = lane + 64 * j;
            sum += fast_tanh(er[h] + ds[h]) * was[h];
        }
        #pragma unroll
        for (int off = 32; off >= 1; off >>= 1) sum += __shfl_xor(sum, off, 64);
        if (lane == 0) sc[s] = sum + bav;
    }
    __syncthreads();

    float x = (tid < len) ? sc[tid] : -INFINITY;
    float m = x;
    #pragma unroll
    for (int off = 32; off >= 1; off >>= 1) m = fmaxf(m, __shfl_xor(m, off, 64));
    if (lane == 0) red[wv] = m;
    __syncthreads();
    m = red[0];
    #pragma unroll
    for (int i = 1; i < 8; i++) m = fmaxf(m, red[i]);
    float e = __expf(x - m);
    float ssum = e;
    #pragma unroll
    for (int off = 32; off >= 1; off >>= 1) ssum += __shfl_xor(ssum, off, 64);
    if (lane == 0) red2[wv] = ssum;
    __syncthreads();
    ssum = red2[0] + red2[1] + red2[2] + red2[3] + red2[4] + red2[5] + red2[6] + red2[7];
    if (tid < 256) sc[tid] = e / ssum;
    __syncthreads();

    {
        const int h  = tid & 255;
        const int sg = tid >> 8;
        const int mid = (len + 1) >> 1;
        const int s0 = sg ? mid : 0;
        const int s1 = sg ? len : mid;
        float cacc = 0.0f;
        const float* eb = enc_raw + (size_t)b * 256 + h;
        #pragma unroll 4
        for (int s = s0; s < s1; s++) cacc += sc[s] * eb[(size_t)s * (B_ * H_)];
        tmp2[tid] = cacc;
    }
    __syncthreads();
    if (tid < 256) {
        float ctx = tmp2[tid] + tmp2[tid + 256];
        ctx_out[((size_t)b * T_ + t) * 256 + tid] = ctx;
        crow[tid] = ctx;
    }
    __syncthreads();

    if (tid < 500) {
        const int v0 = tid * 2;
        float a0 = b_out[v0], a1 = b_out[v0 + 1];
        const uint4* wp = (const uint4*)WoTb + tid;
        #pragma unroll 8
        for (int kq = 0; kq < 128; kq++) {
            uint4 w = wp[(size_t)kq * 500];
            float4 c = *(const float4*)&crow[kq * 4];
            a0 += c.x * blo(w.x); a1 += c.x * bhi(w.x);
            a0 += c.y * blo(w.y); a1 += c.y * bhi(w.y);
            a0 += c.z * blo(w.z); a1 += c.z * bhi(w.z);
            a0 += c.w * blo(w.w); a1 += c.w * bhi(w.w);
        }
        lrow[v0] = a0;
        lrow[v0 + 1] = a1;
    }
    __syncthreads();

    float v0v = -INFINITY, v1v = -INFINITY;
    if (tid < 500) { v0v = lrow[tid * 2]; v1v = lrow[tid * 2 + 1]; }
    float mx = fmaxf(v0v, v1v);
    #pragma unroll
    for (int off = 32; off >= 1; off >>= 1) mx = fmaxf(mx, __shfl_xor(mx, off, 64));
    if (lane == 0) red[wv] = mx;
    __syncthreads();
    mx = red[0];
    #pragma unroll
    for (int i = 1; i < 8; i++) mx = fmaxf(mx, red[i]);
    float e0 = __expf(v0v - mx), e1 = __expf(v1v - mx);
    float s2 = e0 + e1;
    #pragma unroll
    for (int off = 32; off >= 1; off >>= 1) s2 += __shfl_xor(s2, off, 64);
    if (lane == 0) red2[wv] = s2;
    __syncthreads();
    s2 = red2[0] + red2[1] + red2[2] + red2[3] + red2[4] + red2[5] + red2[6] + red2[7];
    float inv = 1.0f / s2;
    if (tid < 500) {
        float2 pv = make_float2(e0 * inv, e1 * inv);
        *(float2*)&probs[((size_t)t * B_ + b) * V_ + tid * 2] = pv;
    }
}

extern "C" void kernel_launch(void* const* d_in, const int* in_sizes, int n_in,
                              void* d_out, int out_size, void* d_ws, size_t ws_size,
                              hipStream_t stream) {
    const int*   tv       = (const int*)d_in[0];
    const float* h0       = (const float*)d_in[1];
    const float* c0       = (const float*)d_in[2];
    const float* enc_raw  = (const float*)d_in[3];
    const int*   lens     = (const int*)d_in[4];
    const float* emb      = (const float*)d_in[5];
    const float* W_ih     = (const float*)d_in[6];
    const float* W_hh     = (const float*)d_in[7];
    const float* b_ih     = (const float*)d_in[8];
    const float* b_hh     = (const float*)d_in[9];
    const float* We       = (const float*)d_in[10];
    const float* be       = (const float*)d_in[11];
    const float* Wd       = (const float*)d_in[12];
    const float* bd       = (const float*)d_in[13];
    const float* wa       = (const float*)d_in[14];
    const float* ba       = (const float*)d_in[15];
    const float* W_out    = (const float*)d_in[16];
    const float* b_out    = (const float*)d_in[17];

    // workspace layout (fp32 words; round-16 proven 14.63 MB footprint)
    float* ws       = (float*)d_ws;
    float* enct     = ws;                       // [8192,256]  2,097,152
    float* xproj    = ws + 2097152;             // [512,1024]    524,288
    float* Wdt      = ws + 2621440;             // float4 [64][256]  65,536 f
    u16*   WoTb     = (u16*)(ws + 2752512);     // uint4 [128][500]  1 MB
    float* combined = ws + 3264512;             // [512,512]     262,144
    u32*   Wt2      = (u32*)(ws + 3526656);     // uint4 [32][1024]  512 KB

    // d_out layout (fp32): probs [T,B,V], hT, cT, ctx [B,T,H]
    float* out      = (float*)d_out;
    float* probs    = out;
    float* hT       = out + 512000;
    float* cT       = out + 520192;
    float* ctx_out  = out + 528384;

    // 1) xproj GEMM (32x64 tiles, 2x parallelism) + Whh->Wt2 transpose
    prep_xproj<<<320, 256, 0, stream>>>(emb, tv, W_ih, b_ih, xproj, W_hh, Wt2);
    // 2) LSTM (waves_per_eu(4,4): unspilled wreg) + enc_t + Wd/Wout transposes
    lstm_enct<<<304, 1024, 0, stream>>>(xproj, Wt2, b_hh, h0, c0, combined, hT, cT,
                                        enc_raw, We, be, enct,
                                        Wd, Wdt, W_out, WoTb);
    // 3) fused attention + logits + vocab softmax (exact round-2, proven)
    attn_logits<<<512, 512, 0, stream>>>(enct, combined, Wdt, bd, enc_raw,
                                         wa, ba, lens, WoTb, b_out, ctx_out, probs);
}